// Round 9
// baseline (412.185 us; speedup 1.0000x reference)
//
#include <hip/hip_runtime.h>

#define NB 4
#define NS 1024
#define NE 512
#define NH 8
#define ND 64
#define NC 16      // chunks per sequence
#define CSZ 64     // chunk size

static constexpr float FEPS = 1e-6f;

typedef _Float16 half_t;
typedef __attribute__((ext_vector_type(8))) _Float16 f16x8;
typedef __attribute__((ext_vector_type(4))) float f32x4;

__device__ __forceinline__ float h_log2kap(int h) {
  float kap = (1.0f - exp2f(-5.0f - (float)h)) * 0.8f;
  return log2f(kap);
}
__device__ __forceinline__ float silu_f(float x) {
  return x / (1.0f + __expf(-x));
}
// async global->LDS, 16 bytes per lane; LDS base must be wave-uniform
__device__ __forceinline__ void gload_lds16(const half_t* g, half_t* l) {
  __builtin_amdgcn_global_load_lds(
      (const __attribute__((address_space(1))) unsigned int*)g,
      (__attribute__((address_space(3))) unsigned int*)l, 16, 0, 0);
}

// -- prep: weight convert+transpose (13 mats) + segment scan + x/obs -> fp16 --
// flat grid: [0,832) weight tiles; [832,836) seg scan (+cnt zero); rest x/obs
struct WCArgs {
  const float* src[13];
  half_t* dst;
  const int* dones;
  int* seg;
  int* cnt;
  const float* x;
  const float* obs;
  half_t* hx;
  half_t* hobs;
};
__global__ __launch_bounds__(256) void prep_kernel(WCArgs a) {
  __shared__ half_t T[64][72];  // [k][n] tile, padded
  __shared__ int s[NS];
  const int t = threadIdx.x;
  const int id = blockIdx.x;
  if (id < 832) {
    const int w = id >> 6;
    const int tile = id & 63;
    const int kt = (tile & 7) * 64;
    const int nt = (tile >> 3) * 64;
    const float* src = a.src[w] + (size_t)kt * NE + nt;
    const int c4 = (t & 15) * 4;
    const int r0 = t >> 4;
#pragma unroll
    for (int rnd = 0; rnd < 4; rnd++) {
      int r = r0 + rnd * 16;
      float4 v = *(const float4*)(src + (size_t)r * NE + c4);
      T[r][c4 + 0] = (half_t)v.x;
      T[r][c4 + 1] = (half_t)v.y;
      T[r][c4 + 2] = (half_t)v.z;
      T[r][c4 + 3] = (half_t)v.w;
    }
    __syncthreads();
    const int n = t >> 2, kq = (t & 3) * 16;
    half_t* dst = a.dst + (size_t)w * NE * NE + (size_t)(nt + n) * NE + kt + kq;
    f16x8 o0, o1;
#pragma unroll
    for (int j = 0; j < 8; j++) {
      o0[j] = T[kq + j][n];
      o1[j] = T[kq + 8 + j][n];
    }
    *(f16x8*)dst = o0;
    *(f16x8*)(dst + 8) = o1;
  } else if (id < 836) {
    const int b = id - 832;
    if (id == 832 && t < 64) a.cnt[t] = 0;  // ticket counters (2 layers' worth)
    for (int i = t; i < NS; i += 256) s[i] = (a.dones[b * NS + i] != 0) ? 1 : 0;
    __syncthreads();
    for (int off = 1; off < NS; off <<= 1) {
      int tv[4];
#pragma unroll
      for (int u = 0; u < 4; u++) {
        int i = t + 256 * u;
        tv[u] = s[i] + ((i >= off) ? s[i - off] : 0);
      }
      __syncthreads();
#pragma unroll
      for (int u = 0; u < 4; u++) s[t + 256 * u] = tv[u];
      __syncthreads();
    }
    for (int i = t; i < NS; i += 256) a.seg[b * NS + i] = s[i];
  } else {
    size_t i = ((size_t)(id - 836) * 256 + t) * 8;
    float4 v0 = *(const float4*)&a.x[i];
    float4 v1 = *(const float4*)&a.x[i + 4];
    f16x8 h;
    h[0] = (half_t)v0.x; h[1] = (half_t)v0.y; h[2] = (half_t)v0.z; h[3] = (half_t)v0.w;
    h[4] = (half_t)v1.x; h[5] = (half_t)v1.y; h[6] = (half_t)v1.z; h[7] = (half_t)v1.w;
    *(f16x8*)&a.hx[i] = h;
    float4 w0 = *(const float4*)&a.obs[i];
    float4 w1 = *(const float4*)&a.obs[i + 4];
    f16x8 g;
    g[0] = (half_t)w0.x; g[1] = (half_t)w0.y; g[2] = (half_t)w0.z; g[3] = (half_t)w0.w;
    g[4] = (half_t)w1.x; g[5] = (half_t)w1.y; g[6] = (half_t)w1.z; g[7] = (half_t)w1.w;
    *(f16x8*)&a.hobs[i] = g;
  }
}

// ---- fp16 MFMA GEMM (TM=64 x 128 tile, BK=64, 4 waves, up to 8 fused GEMMs)
// O[w] = A[w] @ Wt[w]^T * al[w], fp16 out. LDS rows 128B, octet swizzle
// p = o ^ (row&7). 24 KB LDS -> 6 blocks/CU co-resident (latency hiding).
struct GArgs {
  const half_t* A[8];
  const half_t* W[8];
  half_t* O[8];
  float al[8];
};

__global__ __launch_bounds__(256) void mfma_gemm_kernel(GArgs g) {
  __shared__ half_t As[64 * 64];
  __shared__ half_t Bs[128 * 64];
  const int t = threadIdx.x;
  const int bn = blockIdx.x;
  const int wsel = bn >> 2;
  const int n0 = (bn & 3) * 128;
  const int m0 = blockIdx.y * 64;
  const half_t* A = g.A[wsel];
  const half_t* W = g.W[wsel];
  half_t* O = g.O[wsel];
  const float alpha = g.al[wsel];
  const int lane = t & 63;
  const int wv = t >> 6;
  const int frow = lane & 15;
  const int fo = lane >> 4;
  const int mbase = (wv & 1) * 32;
  const int nbase = (wv >> 1) * 64;

  f32x4 acc[2][4];
#pragma unroll
  for (int i = 0; i < 2; i++)
#pragma unroll
    for (int j = 0; j < 4; j++) acc[i][j] = (f32x4){0.f, 0.f, 0.f, 0.f};

  // fragment LDS offsets (halfs): row*64 + (oct ^ (row&7))*8, oct = ks*4+fo
  int offA[2][2], offB[2][4];
#pragma unroll
  for (int ks = 0; ks < 2; ks++) {
#pragma unroll
    for (int f = 0; f < 2; f++) {
      int ra = mbase + f * 16 + frow;
      offA[ks][f] = ra * 64 + (((ks * 4 + fo) ^ (ra & 7)) * 8);
    }
#pragma unroll
    for (int f = 0; f < 4; f++) {
      int rb = nbase + f * 16 + frow;
      offB[ks][f] = rb * 64 + (((ks * 4 + fo) ^ (rb & 7)) * 8);
    }
  }
  // staging: flat f = rnd*256 + t; row = f>>3, phys octet p = f&7,
  // source octet o = p ^ (row&7); dest halfs offset = f*8
  int srow[4], soct[4];
#pragma unroll
  for (int r = 0; r < 4; r++) {
    int f = r * 256 + t;
    srow[r] = f >> 3;
    soct[r] = (f & 7) ^ (srow[r] & 7);
  }
  const int ldsb = (t & 192) * 8;  // wave-uniform base (halfs) within a round

  for (int kt = 0; kt < NE; kt += 64) {
#pragma unroll
    for (int r = 0; r < 2; r++)
      gload_lds16(A + (size_t)(m0 + srow[r]) * NE + kt + soct[r] * 8,
                  &As[r * 2048 + ldsb]);
#pragma unroll
    for (int r = 0; r < 4; r++)
      gload_lds16(W + (size_t)(n0 + srow[r]) * NE + kt + soct[r] * 8,
                  &Bs[r * 2048 + ldsb]);
    __syncthreads();
#pragma unroll
    for (int ks = 0; ks < 2; ks++) {
      f16x8 af[2], bf[4];
#pragma unroll
      for (int f = 0; f < 2; f++) af[f] = *(const f16x8*)&As[offA[ks][f]];
#pragma unroll
      for (int f = 0; f < 4; f++) bf[f] = *(const f16x8*)&Bs[offB[ks][f]];
#pragma unroll
      for (int fm = 0; fm < 2; fm++)
#pragma unroll
        for (int fn = 0; fn < 4; fn++)
          acc[fm][fn] = __builtin_amdgcn_mfma_f32_16x16x32_f16(af[fm], bf[fn], acc[fm][fn], 0, 0, 0);
    }
    __syncthreads();
  }
  // epilogue: C/D layout col=lane&15, row=(lane>>4)*4+reg
#pragma unroll
  for (int fm = 0; fm < 2; fm++) {
    int rb = m0 + mbase + fm * 16 + fo * 4;
#pragma unroll
    for (int fn = 0; fn < 4; fn++) {
      int col = n0 + nbase + fn * 16 + frow;
#pragma unroll
      for (int r = 0; r < 4; r++)
        O[(size_t)(rb + r) * NE + col] = (half_t)(acc[fm][fn][r] * alpha);
    }
  }
}

// ---- fused out-projection + residual RMS norm (full-row blocks) ----
// Block: TM=16 rows x all 512 cols, K=512; 512 threads = 8 waves, each wave
// owns a 64-col slice (4 n-frags). AMODE 0: A fp16 via global_load_lds.
// AMODE 3: silu(A1)*A2 VGPR staging. OMODE 0: fp32; 1: fp16; 2: both.
template <int AMODE, int OMODE>
__global__ __launch_bounds__(512) void oproj_rms_kernel(
    const half_t* __restrict__ A1, const half_t* __restrict__ A2,
    const half_t* __restrict__ W, const float* __restrict__ res,
    const float* __restrict__ scale, float* __restrict__ outf,
    half_t* __restrict__ outh) {
  __shared__ half_t Bs[512 * 64];  // 64 KB
  __shared__ half_t As[16 * 64];
  __shared__ float sls[NE];
  __shared__ float ssb[8][16];
  const int t = threadIdx.x;
  const int m0 = blockIdx.x * 16;
  const int lane = t & 63, wv = t >> 6;
  const int frow = lane & 15, fo = lane >> 4;
  sls[t] = scale[t];

  f32x4 acc[4];
#pragma unroll
  for (int f = 0; f < 4; f++) acc[f] = (f32x4){0.f, 0.f, 0.f, 0.f};

  int offA[2], offB[2][4];
#pragma unroll
  for (int ks = 0; ks < 2; ks++) {
    offA[ks] = frow * 64 + (((ks * 4 + fo) ^ (frow & 7)) * 8);
#pragma unroll
    for (int f = 0; f < 4; f++) {
      int rb = wv * 64 + f * 16 + frow;
      offB[ks][f] = rb * 64 + (((ks * 4 + fo) ^ (rb & 7)) * 8);
    }
  }
  // B staging: 8 rounds x 512 threads; flat f = r*512+t
  int srow[8], soct[8];
#pragma unroll
  for (int r = 0; r < 8; r++) {
    int f = r * 512 + t;
    srow[r] = f >> 3;
    soct[r] = (f & 7) ^ (srow[r] & 7);
  }
  const int ldsbB = (t & 448) * 8;  // wave-uniform base within a round
  // A staging (t<128): flat fa = t; row = t>>3
  const int arow = t >> 3;
  const int aoct = (t & 7) ^ (arow & 7);

  for (int kt = 0; kt < NE; kt += 64) {
    if constexpr (AMODE == 0) {
      if (t < 128)
        gload_lds16(A1 + (size_t)(m0 + arow) * NE + kt + aoct * 8,
                    &As[(t & 64) * 8]);
    } else {  // silu(A1)*A2
      if (t < 128) {
        size_t gofs = (size_t)(m0 + arow) * NE + kt + aoct * 8;
        f16x8 av = *(const f16x8*)(A1 + gofs);
        f16x8 bv = *(const f16x8*)(A2 + gofs);
        f16x8 ov;
#pragma unroll
        for (int e = 0; e < 8; e++)
          ov[e] = (half_t)(silu_f((float)av[e]) * (float)bv[e]);
        *(f16x8*)&As[t * 8] = ov;
      }
    }
#pragma unroll
    for (int r = 0; r < 8; r++)
      gload_lds16(W + (size_t)srow[r] * NE + kt + soct[r] * 8,
                  &Bs[r * 4096 + ldsbB]);
    __syncthreads();
#pragma unroll
    for (int ks = 0; ks < 2; ks++) {
      f16x8 af = *(const f16x8*)&As[offA[ks]];
#pragma unroll
      for (int f = 0; f < 4; f++) {
        f16x8 bf = *(const f16x8*)&Bs[offB[ks][f]];
        acc[f] = __builtin_amdgcn_mfma_f32_16x16x32_f16(af, bf, acc[f], 0, 0, 0);
      }
    }
    __syncthreads();
  }
  // epilogue: row = fo*4+rg, col = wv*64 + f*16 + frow
  float v[4][4];
  float ssp[4] = {0.f, 0.f, 0.f, 0.f};
#pragma unroll
  for (int f = 0; f < 4; f++) {
#pragma unroll
    for (int rg = 0; rg < 4; rg++) {
      int row = fo * 4 + rg;
      int col = wv * 64 + f * 16 + frow;
      float rv = res[(size_t)(m0 + row) * NE + col];
      float xv = acc[f][rg] + rv;
      v[f][rg] = xv;
      ssp[rg] += xv * xv;
    }
  }
#pragma unroll
  for (int rg = 0; rg < 4; rg++) {
    ssp[rg] += __shfl_xor(ssp[rg], 1);
    ssp[rg] += __shfl_xor(ssp[rg], 2);
    ssp[rg] += __shfl_xor(ssp[rg], 4);
    ssp[rg] += __shfl_xor(ssp[rg], 8);
  }
  if (frow == 0) {
#pragma unroll
    for (int rg = 0; rg < 4; rg++) ssb[wv][fo * 4 + rg] = ssp[rg];
  }
  __syncthreads();
#pragma unroll
  for (int rg = 0; rg < 4; rg++) {
    int row = fo * 4 + rg;
    float tot = 0.f;
#pragma unroll
    for (int w = 0; w < 8; w++) tot += ssb[w][row];
    float rsf = rsqrtf(tot * (1.0f / 512.0f) + FEPS);
#pragma unroll
    for (int f = 0; f < 4; f++) {
      int col = wv * 64 + f * 16 + frow;
      float o = v[f][rg] * rsf * sls[col];
      size_t idx = (size_t)(m0 + row) * NE + col;
      if (OMODE == 0 || OMODE == 2) outf[idx] = o;
      if (OMODE == 1 || OMODE == 2) outh[idx] = (half_t)o;
    }
  }
}

// -- retention pass 1 + fused parallel scan (atomic-ticket tail) ------------
// Per (c,bh) block: U_c = K'(w)^T @ V_c (MFMA), f_c -> global; vectorized U
// store via KT bounce. Then __threadfence + atomicAdd ticket; the 16th
// arrival for a bh runs the 4096-chain scan P_{c+1} = f_c*P_c + U_c entirely
// in-kernel (16 chains/thread, coalesced), writes Ph (fp16) + hout (fp32),
// and self-resets the counter for the next launch.
__global__ __launch_bounds__(256) void ret1s_kernel(
    const half_t* __restrict__ kmat, const half_t* __restrict__ vmat,
    const int* __restrict__ seg, const int* __restrict__ ts,
    half_t* __restrict__ U, float* __restrict__ fbuf,
    const float* __restrict__ hin, float* __restrict__ hout,
    half_t* __restrict__ Ph, int* __restrict__ cnt) {
  __shared__ half_t KT[64 * 72];  // w-scaled K^T: [d][j], reused as U bounce
  __shared__ half_t VT[64 * 72];  // V^T: [v][j]
  __shared__ int lastf;
  const int c = blockIdx.x, bh = blockIdx.y;
  const int b = bh >> 3, h = bh & 7;
  const float l2k = h_log2kap(h);
  const int t = threadIdx.x;
  const int r = t & 63, qd = t >> 6;
  const int e = c * CSZ + CSZ - 1;
  const int seg_e = seg[b * NS + e];
  const float ts_e = (float)ts[b * NS + e];
  {
    int gj = b * NS + c * CSZ + r;
    float w = (seg[gj] == seg_e) ? exp2f((ts_e - (float)ts[gj]) * l2k) : 0.0f;
    size_t gbase = (size_t)gj * NE + h * ND + qd * 16;
    f16x8 k0 = *(const f16x8*)&kmat[gbase];
    f16x8 k1 = *(const f16x8*)&kmat[gbase + 8];
    f16x8 v0 = *(const f16x8*)&vmat[gbase];
    f16x8 v1 = *(const f16x8*)&vmat[gbase + 8];
#pragma unroll
    for (int s = 0; s < 8; s++) {
      KT[(qd * 16 + s) * 72 + r] = (half_t)(w * (float)k0[s]);
      KT[(qd * 16 + 8 + s) * 72 + r] = (half_t)(w * (float)k1[s]);
      VT[(qd * 16 + s) * 72 + r] = v0[s];
      VT[(qd * 16 + 8 + s) * 72 + r] = v1[s];
    }
  }
  __syncthreads();
  const int lane = t & 63, wv = t >> 6;
  const int fr = lane & 15, fo8 = (lane >> 4) * 8;
  f32x4 acc[4];
#pragma unroll
  for (int j = 0; j < 4; j++) acc[j] = (f32x4){0.f, 0.f, 0.f, 0.f};
#pragma unroll
  for (int ks = 0; ks < 2; ks++) {
    f16x8 af = *(const f16x8*)&KT[(wv * 16 + fr) * 72 + ks * 32 + fo8];
#pragma unroll
    for (int nt = 0; nt < 4; nt++) {
      f16x8 bf = *(const f16x8*)&VT[(nt * 16 + fr) * 72 + ks * 32 + fo8];
      acc[nt] = __builtin_amdgcn_mfma_f32_16x16x32_f16(af, bf, acc[nt], 0, 0, 0);
    }
  }
  __syncthreads();  // KT reads done; reuse as bounce buffer
  const int drow = wv * 16 + (lane >> 4) * 4;
#pragma unroll
  for (int nt = 0; nt < 4; nt++)
#pragma unroll
    for (int rg = 0; rg < 4; rg++)
      KT[(drow + rg) * 72 + nt * 16 + fr] = (half_t)acc[nt][rg];
  if (t == 0) {
    int ps = 0;
    float pt = -1.0f;
    if (c > 0) {
      ps = seg[b * NS + c * CSZ - 1];
      pt = (float)ts[b * NS + c * CSZ - 1];
    }
    fbuf[bh * NC + c] = (seg_e == ps) ? exp2f((ts_e - pt) * l2k) : 0.0f;
  }
  __syncthreads();
  {
    half_t* Uo = U + ((size_t)bh * NC + c) * (ND * ND);
    int d = t >> 2, v0 = (t & 3) * 16;
    f16x8 u0 = *(const f16x8*)&KT[d * 72 + v0];
    f16x8 u1 = *(const f16x8*)&KT[d * 72 + v0 + 8];
    *(f16x8*)&Uo[d * 64 + v0] = u0;
    *(f16x8*)&Uo[d * 64 + v0 + 8] = u1;
  }
  __threadfence();  // release: U + fbuf visible device-wide
  if (t == 0) {
    int old = atomicAdd(&cnt[bh], 1);
    lastf = (old == NC - 1) ? 1 : 0;
  }
  __syncthreads();
  if (lastf) {
    __threadfence();  // acquire: see all 16 chunks' U + fbuf
    if (t == 0) atomicExch(&cnt[bh], 0);  // reset for next launch
    float P[16];
    const half_t* Ub = U + (size_t)bh * NC * 4096;
    half_t* Pb = Ph + (size_t)bh * NC * 4096;
    const float* fbp = fbuf + bh * NC;
#pragma unroll
    for (int j = 0; j < 16; j++)
      P[j] = hin[(size_t)bh * 4096 + t + j * 256];
    for (int cc = 0; cc < NC; cc++) {
      float f = fbp[cc];
#pragma unroll
      for (int j = 0; j < 16; j++) {
        int i = t + j * 256;
        Pb[(size_t)cc * 4096 + i] = (half_t)P[j];
        P[j] = f * P[j] + (float)Ub[(size_t)cc * 4096 + i];
      }
    }
#pragma unroll
    for (int j = 0; j < 16; j++)
      hout[(size_t)bh * 4096 + t + j * 256] = P[j];
  }
}

// -- retention pass 2+3: per-chunk QK^T decay + inner@V + cross@P + gn + gate.
// P_c comes precomputed (fp16). Vectorized epilogue via PT bounce.
__global__ __launch_bounds__(256) void ret_pass23_kernel(
    const half_t* __restrict__ qmat, const half_t* __restrict__ kmat,
    const half_t* __restrict__ vmat, const half_t* __restrict__ Ph,
    const half_t* __restrict__ gmat, const int* __restrict__ seg,
    const int* __restrict__ ts, const float* __restrict__ gns,
    const float* __restrict__ gnb, half_t* __restrict__ y16) {
  __shared__ half_t Qs[64 * 72];
  __shared__ half_t KS[64 * 72];
  __shared__ half_t VT[64 * 72];
  __shared__ half_t PT[64 * 72];
  __shared__ int segs[64];
  __shared__ int tss[64];
  __shared__ float gnsv[64];
  __shared__ float gnbv[64];
  const int c = blockIdx.x, bh = blockIdx.y;
  const int b = bh >> 3, h = bh & 7;
  const float l2k = h_log2kap(h);
  const int t = threadIdx.x;
  const int r = t & 63, qd = t >> 6;
  {
    size_t gbase = (size_t)(b * NS + c * CSZ + r) * NE + h * ND + qd * 16;
    f16x8 q0 = *(const f16x8*)&qmat[gbase];
    f16x8 q1 = *(const f16x8*)&qmat[gbase + 8];
    *(f16x8*)&Qs[r * 72 + qd * 16] = q0;
    *(f16x8*)&Qs[r * 72 + qd * 16 + 8] = q1;
    f16x8 k0 = *(const f16x8*)&kmat[gbase];
    f16x8 k1 = *(const f16x8*)&kmat[gbase + 8];
    *(f16x8*)&KS[r * 72 + qd * 16] = k0;
    *(f16x8*)&KS[r * 72 + qd * 16 + 8] = k1;
    f16x8 v0 = *(const f16x8*)&vmat[gbase];
    f16x8 v1 = *(const f16x8*)&vmat[gbase + 8];
    const half_t* php = Ph + ((size_t)bh * NC + c) * 4096 + r * 64 + qd * 16;
    f16x8 p0 = *(const f16x8*)php;
    f16x8 p1 = *(const f16x8*)(php + 8);
#pragma unroll
    for (int s = 0; s < 8; s++) {
      VT[(qd * 16 + s) * 72 + r] = v0[s];
      VT[(qd * 16 + 8 + s) * 72 + r] = v1[s];
      PT[(qd * 16 + s) * 72 + r] = p0[s];
      PT[(qd * 16 + 8 + s) * 72 + r] = p1[s];
    }
    if (t < 64) {
      segs[t] = seg[b * NS + c * CSZ + t];
      tss[t] = ts[b * NS + c * CSZ + t];
    } else if (t < 128) {
      gnsv[t - 64] = gns[h * ND + t - 64];
      gnbv[t - 64] = gnb[h * ND + t - 64];
    }
  }
  __syncthreads();
  const int lane = t & 63, wv = t >> 6;
  const int fr = lane & 15, fo8 = (lane >> 4) * 8;
  f32x4 aq[4];
#pragma unroll
  for (int j = 0; j < 4; j++) aq[j] = (f32x4){0.f, 0.f, 0.f, 0.f};
#pragma unroll
  for (int ks = 0; ks < 2; ks++) {
    f16x8 af = *(const f16x8*)&Qs[(wv * 16 + fr) * 72 + ks * 32 + fo8];
#pragma unroll
    for (int nt = 0; nt < 4; nt++) {
      f16x8 bf = *(const f16x8*)&KS[(nt * 16 + fr) * 72 + ks * 32 + fo8];
      aq[nt] = __builtin_amdgcn_mfma_f32_16x16x32_f16(af, bf, aq[nt], 0, 0, 0);
    }
  }
  __syncthreads();
  const int qrow = wv * 16 + (lane >> 4) * 4;
#pragma unroll
  for (int nt = 0; nt < 4; nt++) {
    int j = nt * 16 + fr;
    int sj = segs[j];
    float tsj = (float)tss[j];
#pragma unroll
    for (int rg = 0; rg < 4; rg++) {
      int i = qrow + rg;
      float w = 0.0f;
      if (j <= i && sj == segs[i]) w = exp2f(((float)tss[i] - tsj) * l2k);
      KS[i * 72 + j] = (half_t)(aq[nt][rg] * w);
    }
  }
  __syncthreads();
  float gi;
  {
    int ps = 0;
    float pt = -1.0f;
    if (c > 0) {
      ps = seg[b * NS + c * CSZ - 1];
      pt = (float)ts[b * NS + c * CSZ - 1];
    }
    int i = wv * 16 + fr;
    gi = (segs[i] == ps) ? exp2f(((float)tss[i] - pt) * l2k) : 0.0f;
  }
  f32x4 acc[4];
#pragma unroll
  for (int j = 0; j < 4; j++) acc[j] = (f32x4){0.f, 0.f, 0.f, 0.f};
#pragma unroll
  for (int ks = 0; ks < 2; ks++) {
    f16x8 saf = *(const f16x8*)&KS[(wv * 16 + fr) * 72 + ks * 32 + fo8];
    f16x8 qaf = *(const f16x8*)&Qs[(wv * 16 + fr) * 72 + ks * 32 + fo8];
    f16x8 gqf;
#pragma unroll
    for (int e = 0; e < 8; e++) gqf[e] = (half_t)(gi * (float)qaf[e]);
#pragma unroll
    for (int nt = 0; nt < 4; nt++) {
      f16x8 vbf = *(const f16x8*)&VT[(nt * 16 + fr) * 72 + ks * 32 + fo8];
      acc[nt] = __builtin_amdgcn_mfma_f32_16x16x32_f16(saf, vbf, acc[nt], 0, 0, 0);
      f16x8 pbf = *(const f16x8*)&PT[(nt * 16 + fr) * 72 + ks * 32 + fo8];
      acc[nt] = __builtin_amdgcn_mfma_f32_16x16x32_f16(gqf, pbf, acc[nt], 0, 0, 0);
    }
  }
  __syncthreads();  // PT reads done; reuse as epilogue bounce
#pragma unroll
  for (int rg = 0; rg < 4; rg++) {
    float s1 = acc[0][rg] + acc[1][rg] + acc[2][rg] + acc[3][rg];
    float s2 = acc[0][rg] * acc[0][rg] + acc[1][rg] * acc[1][rg] +
               acc[2][rg] * acc[2][rg] + acc[3][rg] * acc[3][rg];
    s1 += __shfl_xor(s1, 1); s2 += __shfl_xor(s2, 1);
    s1 += __shfl_xor(s1, 2); s2 += __shfl_xor(s2, 2);
    s1 += __shfl_xor(s1, 4); s2 += __shfl_xor(s2, 4);
    s1 += __shfl_xor(s1, 8); s2 += __shfl_xor(s2, 8);
    float mu = s1 * (1.0f / 64.0f);
    float var = s2 * (1.0f / 64.0f) - mu * mu;
    float rs = rsqrtf(var + FEPS);
    int i = qrow + rg;
#pragma unroll
    for (int nt = 0; nt < 4; nt++) {
      int col = nt * 16 + fr;
      PT[i * 72 + col] = (half_t)((acc[nt][rg] - mu) * rs * gnsv[col] + gnbv[col]);
    }
  }
  __syncthreads();
  {
    int row = t >> 2, col0 = (t & 3) * 16;
    size_t gb2 = (size_t)(b * NS + c * CSZ + row) * NE + h * ND + col0;
    f16x8 g0 = *(const f16x8*)&gmat[gb2];
    f16x8 g1 = *(const f16x8*)&gmat[gb2 + 8];
    f16x8 v0 = *(const f16x8*)&PT[row * 72 + col0];
    f16x8 v1 = *(const f16x8*)&PT[row * 72 + col0 + 8];
    f16x8 o0, o1;
#pragma unroll
    for (int e2 = 0; e2 < 8; e2++) {
      o0[e2] = (half_t)(silu_f((float)g0[e2]) * (float)v0[e2]);
      o1[e2] = (half_t)(silu_f((float)g1[e2]) * (float)v1[e2]);
    }
    *(f16x8*)&y16[gb2] = o0;
    *(f16x8*)&y16[gb2 + 8] = o1;
  }
}

extern "C" void kernel_launch(void* const* d_in, const int* in_sizes, int n_in,
                              void* d_out, int out_size, void* d_ws, size_t ws_size,
                              hipStream_t stream) {
  (void)in_sizes; (void)n_in; (void)out_size; (void)ws_size;
  const float* x = (const float*)d_in[0];
  const float* obs = (const float*)d_in[1];
  const float* hs1 = (const float*)d_in[2];
  const float* hs2 = (const float*)d_in[3];
  const int* dones = (const int*)d_in[4];
  const int* tsid = (const int*)d_in[5];
  const float* ln1 = (const float*)d_in[6];
  const float* ln2 = (const float*)d_in[7];
  const float* ln3 = (const float*)d_in[8];
  const float* r1_gs = (const float*)d_in[14];
  const float* r1_gb = (const float*)d_in[15];
  const float* r2_gs = (const float*)d_in[21];
  const float* r2_gb = (const float*)d_in[22];

  const size_t NBUF = (size_t)NB * NS * NE;  // 2,097,152 elements
  char* ws = (char*)d_ws;
  int* segb = (int*)ws;                              // 16 KB
  float* fb = (float*)(ws + 16384);                  // 2 KB
  int* cntb = (int*)(ws + 18432);                    // 256 B (ticket counters)
  half_t* W16 = (half_t*)(ws + 18688);               // 13 x 512 KB
  char* p = ws + 18688 + (size_t)13 * NE * NE * sizeof(half_t);
  float* F1 = (float*)p;                 // y (fp32 residual for final rms)
  half_t* Uh = (half_t*)(F1 + NBUF);     // U (fp16), 4 MB
  half_t* Ph = Uh + NBUF;                // P_c scan states (fp16), 4 MB
  half_t* Hq = Ph + NBUF;
  half_t* Hk = Hq + NBUF;
  half_t* Hv = Hk + NBUF;
  half_t* Hg = Hv + NBUF;
  half_t* H1 = Hg + NBUF;                // pass3 output (gated, fp16)
  half_t* H2 = H1 + NBUF;                // rms fp16 output
  half_t* Hx = H2 + NBUF;                // x fp16
  half_t* Hobs = Hx + NBUF;              // obs fp16
  half_t* Hq2 = Hobs + NBUF;             // layer-2 q (computed early)
  half_t* Hg2 = Hq2 + NBUF;              // layer-2 g (computed early)

  float* out = (float*)d_out;
  float* hs1o = out + NBUF;
  float* hs2o = hs1o + (size_t)NB * NH * ND * ND;

  WCArgs wc;
  wc.src[0] = (const float*)d_in[9];   wc.src[1] = (const float*)d_in[10];
  wc.src[2] = (const float*)d_in[11];  wc.src[3] = (const float*)d_in[12];
  wc.src[4] = (const float*)d_in[13];  wc.src[5] = (const float*)d_in[16];
  wc.src[6] = (const float*)d_in[17];  wc.src[7] = (const float*)d_in[18];
  wc.src[8] = (const float*)d_in[19];  wc.src[9] = (const float*)d_in[20];
  wc.src[10] = (const float*)d_in[24]; wc.src[11] = (const float*)d_in[23];
  wc.src[12] = (const float*)d_in[25];
  wc.dst = W16;
  wc.dones = dones;
  wc.seg = segb;
  wc.cnt = cntb;
  wc.x = x; wc.obs = obs; wc.hx = Hx; wc.hobs = Hobs;
  const half_t* WS[13];
  for (int i = 0; i < 13; i++) WS[i] = W16 + (size_t)i * NE * NE;

  dim3 gR(16, 32);

  prep_kernel<<<1860, 256, 0, stream>>>(wc);

  // ---- GEMM-1 (6 fused): layer1 q,k,v,g from x16; layer2 q2,g2 from obs16 ----
  {
    GArgs a;
    a.A[0] = Hx;   a.W[0] = WS[0]; a.O[0] = Hq;  a.al[0] = 1.0f;
    a.A[1] = Hx;   a.W[1] = WS[1]; a.O[1] = Hk;  a.al[1] = 0.125f;
    a.A[2] = Hx;   a.W[2] = WS[2]; a.O[2] = Hv;  a.al[2] = 1.0f;
    a.A[3] = Hx;   a.W[3] = WS[3]; a.O[3] = Hg;  a.al[3] = 1.0f;
    a.A[4] = Hobs; a.W[4] = WS[5]; a.O[4] = Hq2; a.al[4] = 1.0f;
    a.A[5] = Hobs; a.W[5] = WS[8]; a.O[5] = Hg2; a.al[5] = 1.0f;
    a.A[6] = Hx;   a.W[6] = WS[0]; a.O[6] = Hq;  a.al[6] = 1.0f;  // unused
    a.A[7] = Hx;   a.W[7] = WS[0]; a.O[7] = Hq;  a.al[7] = 1.0f;  // unused
    mfma_gemm_kernel<<<dim3(24, 64), 256, 0, stream>>>(a);
  }
  ret1s_kernel<<<gR, 256, 0, stream>>>(Hk, Hv, segb, tsid, Uh, fb, hs1, hs1o,
                                       Ph, cntb);
  ret_pass23_kernel<<<gR, 256, 0, stream>>>(Hq, Hk, Hv, Ph, Hg, segb, tsid,
                                            r1_gs, r1_gb, H1);
  // o1 + rms1 fused: x2 = rms(x + H1@wo1) -> H2 (fp16)
  oproj_rms_kernel<0, 1><<<256, 512, 0, stream>>>(H1, nullptr, WS[4], x, ln1,
                                                  nullptr, H2);

  // ---- GEMM-2 (2 fused): k2,v2 = x2 @ {wk2,wv2} ----
  {
    GArgs a;
    a.A[0] = H2; a.W[0] = WS[6]; a.O[0] = Hk; a.al[0] = 0.125f;
    a.A[1] = H2; a.W[1] = WS[7]; a.O[1] = Hv; a.al[1] = 1.0f;
    a.A[2] = H2; a.W[2] = WS[6]; a.O[2] = Hk; a.al[2] = 0.125f;  // unused
    a.A[3] = H2; a.W[3] = WS[6]; a.O[3] = Hk; a.al[3] = 0.125f;  // unused
    a.A[4] = H2; a.W[4] = WS[6]; a.O[4] = Hk; a.al[4] = 0.125f;
    a.A[5] = H2; a.W[5] = WS[6]; a.O[5] = Hk; a.al[5] = 0.125f;
    a.A[6] = H2; a.W[6] = WS[6]; a.O[6] = Hk; a.al[6] = 0.125f;
    a.A[7] = H2; a.W[7] = WS[6]; a.O[7] = Hk; a.al[7] = 0.125f;
    mfma_gemm_kernel<<<dim3(8, 64), 256, 0, stream>>>(a);
  }
  ret1s_kernel<<<gR, 256, 0, stream>>>(Hk, Hv, segb, tsid, Uh, fb, hs2, hs2o,
                                       Ph, cntb);
  ret_pass23_kernel<<<gR, 256, 0, stream>>>(Hq2, Hk, Hv, Ph, Hg2, segb, tsid,
                                            r2_gs, r2_gb, H1);
  // o2 + rms2 fused: y = rms(obs + H1@wo2) -> F1 (fp32) + H2 (fp16)
  oproj_rms_kernel<0, 2><<<256, 512, 0, stream>>>(H1, nullptr, WS[9], obs, ln2,
                                                  F1, H2);

  // ---- FFN part A (2 fused): gate = y@wg -> Hq, lin = y@wl -> Hk ----
  {
    GArgs a;
    a.A[0] = H2; a.W[0] = WS[10]; a.O[0] = Hq; a.al[0] = 1.0f;
    a.A[1] = H2; a.W[1] = WS[11]; a.O[1] = Hk; a.al[1] = 1.0f;
    a.A[2] = H2; a.W[2] = WS[10]; a.O[2] = Hq; a.al[2] = 1.0f;  // unused
    a.A[3] = H2; a.W[3] = WS[10]; a.O[3] = Hq; a.al[3] = 1.0f;  // unused
    a.A[4] = H2; a.W[4] = WS[10]; a.O[4] = Hq; a.al[4] = 1.0f;
    a.A[5] = H2; a.W[5] = WS[10]; a.O[5] = Hq; a.al[5] = 1.0f;
    a.A[6] = H2; a.W[6] = WS[10]; a.O[6] = Hq; a.al[6] = 1.0f;
    a.A[7] = H2; a.W[7] = WS[10]; a.O[7] = Hq; a.al[7] = 1.0f;
    mfma_gemm_kernel<<<dim3(8, 64), 256, 0, stream>>>(a);
  }
  // FFN part B + final rms fused: out = rms(y + (silu(Hq)*Hk)@wo3)
  oproj_rms_kernel<3, 0><<<256, 512, 0, stream>>>(Hq, Hk, WS[12], F1, ln3,
                                                  out, nullptr);
}

// Round 10
// 243.062 us; speedup vs baseline: 1.6958x; 1.6958x over previous
//
#include <hip/hip_runtime.h>

#define NB 4
#define NS 1024
#define NE 512
#define NH 8
#define ND 64
#define NC 16      // chunks per sequence
#define CSZ 64     // chunk size

static constexpr float FEPS = 1e-6f;

typedef _Float16 half_t;
typedef __attribute__((ext_vector_type(8))) _Float16 f16x8;
typedef __attribute__((ext_vector_type(4))) float f32x4;

__device__ __forceinline__ float h_log2kap(int h) {
  float kap = (1.0f - exp2f(-5.0f - (float)h)) * 0.8f;
  return log2f(kap);
}
__device__ __forceinline__ float silu_f(float x) {
  return x / (1.0f + __expf(-x));
}
// async global->LDS, 16 bytes per lane; LDS base must be wave-uniform
__device__ __forceinline__ void gload_lds16(const half_t* g, half_t* l) {
  __builtin_amdgcn_global_load_lds(
      (const __attribute__((address_space(1))) unsigned int*)g,
      (__attribute__((address_space(3))) unsigned int*)l, 16, 0, 0);
}

// -- prep: weight convert+transpose (13 mats) + segment scan + x/obs -> fp16 --
// flat grid: [0,832) weight tiles; [832,836) seg scan; [836,1860) x/obs convert
struct WCArgs {
  const float* src[13];
  half_t* dst;
  const int* dones;
  int* seg;
  const float* x;
  const float* obs;
  half_t* hx;
  half_t* hobs;
};
__global__ __launch_bounds__(256) void prep_kernel(WCArgs a) {
  __shared__ half_t T[64][72];  // [k][n] tile, padded
  __shared__ int s[NS];
  const int t = threadIdx.x;
  const int id = blockIdx.x;
  if (id < 832) {
    const int w = id >> 6;
    const int tile = id & 63;
    const int kt = (tile & 7) * 64;
    const int nt = (tile >> 3) * 64;
    const float* src = a.src[w] + (size_t)kt * NE + nt;
    const int c4 = (t & 15) * 4;
    const int r0 = t >> 4;
#pragma unroll
    for (int rnd = 0; rnd < 4; rnd++) {
      int r = r0 + rnd * 16;
      float4 v = *(const float4*)(src + (size_t)r * NE + c4);
      T[r][c4 + 0] = (half_t)v.x;
      T[r][c4 + 1] = (half_t)v.y;
      T[r][c4 + 2] = (half_t)v.z;
      T[r][c4 + 3] = (half_t)v.w;
    }
    __syncthreads();
    const int n = t >> 2, kq = (t & 3) * 16;
    half_t* dst = a.dst + (size_t)w * NE * NE + (size_t)(nt + n) * NE + kt + kq;
    f16x8 o0, o1;
#pragma unroll
    for (int j = 0; j < 8; j++) {
      o0[j] = T[kq + j][n];
      o1[j] = T[kq + 8 + j][n];
    }
    *(f16x8*)dst = o0;
    *(f16x8*)(dst + 8) = o1;
  } else if (id < 836) {
    const int b = id - 832;
    for (int i = t; i < NS; i += 256) s[i] = (a.dones[b * NS + i] != 0) ? 1 : 0;
    __syncthreads();
    for (int off = 1; off < NS; off <<= 1) {
      int tv[4];
#pragma unroll
      for (int u = 0; u < 4; u++) {
        int i = t + 256 * u;
        tv[u] = s[i] + ((i >= off) ? s[i - off] : 0);
      }
      __syncthreads();
#pragma unroll
      for (int u = 0; u < 4; u++) s[t + 256 * u] = tv[u];
      __syncthreads();
    }
    for (int i = t; i < NS; i += 256) a.seg[b * NS + i] = s[i];
  } else {
    size_t i = ((size_t)(id - 836) * 256 + t) * 8;
    float4 v0 = *(const float4*)&a.x[i];
    float4 v1 = *(const float4*)&a.x[i + 4];
    f16x8 h;
    h[0] = (half_t)v0.x; h[1] = (half_t)v0.y; h[2] = (half_t)v0.z; h[3] = (half_t)v0.w;
    h[4] = (half_t)v1.x; h[5] = (half_t)v1.y; h[6] = (half_t)v1.z; h[7] = (half_t)v1.w;
    *(f16x8*)&a.hx[i] = h;
    float4 w0 = *(const float4*)&a.obs[i];
    float4 w1 = *(const float4*)&a.obs[i + 4];
    f16x8 g;
    g[0] = (half_t)w0.x; g[1] = (half_t)w0.y; g[2] = (half_t)w0.z; g[3] = (half_t)w0.w;
    g[4] = (half_t)w1.x; g[5] = (half_t)w1.y; g[6] = (half_t)w1.z; g[7] = (half_t)w1.w;
    *(f16x8*)&a.hobs[i] = g;
  }
}

// ---- fp16 MFMA GEMM (TM=64 x 128 tile, BK=64, 4 waves, up to 8 fused GEMMs)
// O[w] = A[w] @ Wt[w]^T * al[w], fp16 out. LDS rows 128B, octet swizzle
// p = o ^ (row&7). 24 KB LDS -> 6 blocks/CU co-resident (latency hiding).
struct GArgs {
  const half_t* A[8];
  const half_t* W[8];
  half_t* O[8];
  float al[8];
};

__global__ __launch_bounds__(256) void mfma_gemm_kernel(GArgs g) {
  __shared__ half_t As[64 * 64];
  __shared__ half_t Bs[128 * 64];
  const int t = threadIdx.x;
  const int bn = blockIdx.x;
  const int wsel = bn >> 2;
  const int n0 = (bn & 3) * 128;
  const int m0 = blockIdx.y * 64;
  const half_t* A = g.A[wsel];
  const half_t* W = g.W[wsel];
  half_t* O = g.O[wsel];
  const float alpha = g.al[wsel];
  const int lane = t & 63;
  const int wv = t >> 6;
  const int frow = lane & 15;
  const int fo = lane >> 4;
  const int mbase = (wv & 1) * 32;
  const int nbase = (wv >> 1) * 64;

  f32x4 acc[2][4];
#pragma unroll
  for (int i = 0; i < 2; i++)
#pragma unroll
    for (int j = 0; j < 4; j++) acc[i][j] = (f32x4){0.f, 0.f, 0.f, 0.f};

  // fragment LDS offsets (halfs): row*64 + (oct ^ (row&7))*8, oct = ks*4+fo
  int offA[2][2], offB[2][4];
#pragma unroll
  for (int ks = 0; ks < 2; ks++) {
#pragma unroll
    for (int f = 0; f < 2; f++) {
      int ra = mbase + f * 16 + frow;
      offA[ks][f] = ra * 64 + (((ks * 4 + fo) ^ (ra & 7)) * 8);
    }
#pragma unroll
    for (int f = 0; f < 4; f++) {
      int rb = nbase + f * 16 + frow;
      offB[ks][f] = rb * 64 + (((ks * 4 + fo) ^ (rb & 7)) * 8);
    }
  }
  // staging: flat f = rnd*256 + t; row = f>>3, phys octet p = f&7,
  // source octet o = p ^ (row&7); dest halfs offset = f*8
  int srow[4], soct[4];
#pragma unroll
  for (int r = 0; r < 4; r++) {
    int f = r * 256 + t;
    srow[r] = f >> 3;
    soct[r] = (f & 7) ^ (srow[r] & 7);
  }
  const int ldsb = (t & 192) * 8;  // wave-uniform base (halfs) within a round

  for (int kt = 0; kt < NE; kt += 64) {
#pragma unroll
    for (int r = 0; r < 2; r++)
      gload_lds16(A + (size_t)(m0 + srow[r]) * NE + kt + soct[r] * 8,
                  &As[r * 2048 + ldsb]);
#pragma unroll
    for (int r = 0; r < 4; r++)
      gload_lds16(W + (size_t)(n0 + srow[r]) * NE + kt + soct[r] * 8,
                  &Bs[r * 2048 + ldsb]);
    __syncthreads();
#pragma unroll
    for (int ks = 0; ks < 2; ks++) {
      f16x8 af[2], bf[4];
#pragma unroll
      for (int f = 0; f < 2; f++) af[f] = *(const f16x8*)&As[offA[ks][f]];
#pragma unroll
      for (int f = 0; f < 4; f++) bf[f] = *(const f16x8*)&Bs[offB[ks][f]];
#pragma unroll
      for (int fm = 0; fm < 2; fm++)
#pragma unroll
        for (int fn = 0; fn < 4; fn++)
          acc[fm][fn] = __builtin_amdgcn_mfma_f32_16x16x32_f16(af[fm], bf[fn], acc[fm][fn], 0, 0, 0);
    }
    __syncthreads();
  }
  // epilogue: C/D layout col=lane&15, row=(lane>>4)*4+reg
#pragma unroll
  for (int fm = 0; fm < 2; fm++) {
    int rb = m0 + mbase + fm * 16 + fo * 4;
#pragma unroll
    for (int fn = 0; fn < 4; fn++) {
      int col = n0 + nbase + fn * 16 + frow;
#pragma unroll
      for (int r = 0; r < 4; r++)
        O[(size_t)(rb + r) * NE + col] = (half_t)(acc[fm][fn][r] * alpha);
    }
  }
}

// ---- fused out-projection + residual RMS norm (full-row blocks) ----
// Block: TM=16 rows x all 512 cols, K=512; 512 threads = 8 waves, each wave
// owns a 64-col slice (4 n-frags). AMODE 0: A fp16 via global_load_lds.
// AMODE 3: silu(A1)*A2 VGPR staging. OMODE 0: fp32; 1: fp16; 2: both.
template <int AMODE, int OMODE>
__global__ __launch_bounds__(512) void oproj_rms_kernel(
    const half_t* __restrict__ A1, const half_t* __restrict__ A2,
    const half_t* __restrict__ W, const float* __restrict__ res,
    const float* __restrict__ scale, float* __restrict__ outf,
    half_t* __restrict__ outh) {
  __shared__ half_t Bs[512 * 64];  // 64 KB
  __shared__ half_t As[16 * 64];
  __shared__ float sls[NE];
  __shared__ float ssb[8][16];
  const int t = threadIdx.x;
  const int m0 = blockIdx.x * 16;
  const int lane = t & 63, wv = t >> 6;
  const int frow = lane & 15, fo = lane >> 4;
  sls[t] = scale[t];

  f32x4 acc[4];
#pragma unroll
  for (int f = 0; f < 4; f++) acc[f] = (f32x4){0.f, 0.f, 0.f, 0.f};

  int offA[2], offB[2][4];
#pragma unroll
  for (int ks = 0; ks < 2; ks++) {
    offA[ks] = frow * 64 + (((ks * 4 + fo) ^ (frow & 7)) * 8);
#pragma unroll
    for (int f = 0; f < 4; f++) {
      int rb = wv * 64 + f * 16 + frow;
      offB[ks][f] = rb * 64 + (((ks * 4 + fo) ^ (rb & 7)) * 8);
    }
  }
  // B staging: 8 rounds x 512 threads; flat f = r*512+t
  int srow[8], soct[8];
#pragma unroll
  for (int r = 0; r < 8; r++) {
    int f = r * 512 + t;
    srow[r] = f >> 3;
    soct[r] = (f & 7) ^ (srow[r] & 7);
  }
  const int ldsbB = (t & 448) * 8;  // wave-uniform base within a round
  // A staging (t<128): flat fa = t; row = t>>3
  const int arow = t >> 3;
  const int aoct = (t & 7) ^ (arow & 7);

  for (int kt = 0; kt < NE; kt += 64) {
    if constexpr (AMODE == 0) {
      if (t < 128)
        gload_lds16(A1 + (size_t)(m0 + arow) * NE + kt + aoct * 8,
                    &As[(t & 64) * 8]);
    } else {  // silu(A1)*A2
      if (t < 128) {
        size_t gofs = (size_t)(m0 + arow) * NE + kt + aoct * 8;
        f16x8 av = *(const f16x8*)(A1 + gofs);
        f16x8 bv = *(const f16x8*)(A2 + gofs);
        f16x8 ov;
#pragma unroll
        for (int e = 0; e < 8; e++)
          ov[e] = (half_t)(silu_f((float)av[e]) * (float)bv[e]);
        *(f16x8*)&As[t * 8] = ov;
      }
    }
#pragma unroll
    for (int r = 0; r < 8; r++)
      gload_lds16(W + (size_t)srow[r] * NE + kt + soct[r] * 8,
                  &Bs[r * 4096 + ldsbB]);
    __syncthreads();
#pragma unroll
    for (int ks = 0; ks < 2; ks++) {
      f16x8 af = *(const f16x8*)&As[offA[ks]];
#pragma unroll
      for (int f = 0; f < 4; f++) {
        f16x8 bf = *(const f16x8*)&Bs[offB[ks][f]];
        acc[f] = __builtin_amdgcn_mfma_f32_16x16x32_f16(af, bf, acc[f], 0, 0, 0);
      }
    }
    __syncthreads();
  }
  // epilogue: row = fo*4+rg, col = wv*64 + f*16 + frow
  float v[4][4];
  float ssp[4] = {0.f, 0.f, 0.f, 0.f};
#pragma unroll
  for (int f = 0; f < 4; f++) {
#pragma unroll
    for (int rg = 0; rg < 4; rg++) {
      int row = fo * 4 + rg;
      int col = wv * 64 + f * 16 + frow;
      float rv = res[(size_t)(m0 + row) * NE + col];
      float xv = acc[f][rg] + rv;
      v[f][rg] = xv;
      ssp[rg] += xv * xv;
    }
  }
#pragma unroll
  for (int rg = 0; rg < 4; rg++) {
    ssp[rg] += __shfl_xor(ssp[rg], 1);
    ssp[rg] += __shfl_xor(ssp[rg], 2);
    ssp[rg] += __shfl_xor(ssp[rg], 4);
    ssp[rg] += __shfl_xor(ssp[rg], 8);
  }
  if (frow == 0) {
#pragma unroll
    for (int rg = 0; rg < 4; rg++) ssb[wv][fo * 4 + rg] = ssp[rg];
  }
  __syncthreads();
#pragma unroll
  for (int rg = 0; rg < 4; rg++) {
    int row = fo * 4 + rg;
    float tot = 0.f;
#pragma unroll
    for (int w = 0; w < 8; w++) tot += ssb[w][row];
    float rsf = rsqrtf(tot * (1.0f / 512.0f) + FEPS);
#pragma unroll
    for (int f = 0; f < 4; f++) {
      int col = wv * 64 + f * 16 + frow;
      float o = v[f][rg] * rsf * sls[col];
      size_t idx = (size_t)(m0 + row) * NE + col;
      if (OMODE == 0 || OMODE == 2) outf[idx] = o;
      if (OMODE == 1 || OMODE == 2) outh[idx] = (half_t)o;
    }
  }
}

// ------- retention pass 1 (MFMA): U_c[d][v] (fp16 out) + carry factor f ------
// Vectorized U store via KT bounce (2x16B per thread). NO device-scope
// fences/atomics: measured 100 us/launch cost on this 8-XCD part (round 9).
__global__ __launch_bounds__(256) void ret_pass1_kernel(
    const half_t* __restrict__ kmat, const half_t* __restrict__ vmat,
    const int* __restrict__ seg, const int* __restrict__ ts,
    half_t* __restrict__ U, float* __restrict__ fbuf) {
  __shared__ half_t KT[64 * 72];  // w-scaled K^T: [d][j], reused as U bounce
  __shared__ half_t VT[64 * 72];  // V^T: [v][j]
  const int c = blockIdx.x, bh = blockIdx.y;
  const int b = bh >> 3, h = bh & 7;
  const float l2k = h_log2kap(h);
  const int t = threadIdx.x;
  const int r = t & 63, qd = t >> 6;
  const int e = c * CSZ + CSZ - 1;
  const int seg_e = seg[b * NS + e];
  const float ts_e = (float)ts[b * NS + e];
  {
    int gj = b * NS + c * CSZ + r;
    float w = (seg[gj] == seg_e) ? exp2f((ts_e - (float)ts[gj]) * l2k) : 0.0f;
    size_t gbase = (size_t)gj * NE + h * ND + qd * 16;
    f16x8 k0 = *(const f16x8*)&kmat[gbase];
    f16x8 k1 = *(const f16x8*)&kmat[gbase + 8];
    f16x8 v0 = *(const f16x8*)&vmat[gbase];
    f16x8 v1 = *(const f16x8*)&vmat[gbase + 8];
#pragma unroll
    for (int s = 0; s < 8; s++) {
      KT[(qd * 16 + s) * 72 + r] = (half_t)(w * (float)k0[s]);
      KT[(qd * 16 + 8 + s) * 72 + r] = (half_t)(w * (float)k1[s]);
      VT[(qd * 16 + s) * 72 + r] = v0[s];
      VT[(qd * 16 + 8 + s) * 72 + r] = v1[s];
    }
  }
  __syncthreads();
  const int lane = t & 63, wv = t >> 6;
  const int fr = lane & 15, fo8 = (lane >> 4) * 8;
  f32x4 acc[4];
#pragma unroll
  for (int j = 0; j < 4; j++) acc[j] = (f32x4){0.f, 0.f, 0.f, 0.f};
#pragma unroll
  for (int ks = 0; ks < 2; ks++) {
    f16x8 af = *(const f16x8*)&KT[(wv * 16 + fr) * 72 + ks * 32 + fo8];
#pragma unroll
    for (int nt = 0; nt < 4; nt++) {
      f16x8 bf = *(const f16x8*)&VT[(nt * 16 + fr) * 72 + ks * 32 + fo8];
      acc[nt] = __builtin_amdgcn_mfma_f32_16x16x32_f16(af, bf, acc[nt], 0, 0, 0);
    }
  }
  __syncthreads();  // KT reads done; reuse as bounce buffer
  const int drow = wv * 16 + (lane >> 4) * 4;
#pragma unroll
  for (int nt = 0; nt < 4; nt++)
#pragma unroll
    for (int rg = 0; rg < 4; rg++)
      KT[(drow + rg) * 72 + nt * 16 + fr] = (half_t)acc[nt][rg];
  if (t == 0) {
    int ps = 0;
    float pt = -1.0f;
    if (c > 0) {
      ps = seg[b * NS + c * CSZ - 1];
      pt = (float)ts[b * NS + c * CSZ - 1];
    }
    fbuf[bh * NC + c] = (seg_e == ps) ? exp2f((ts_e - pt) * l2k) : 0.0f;
  }
  __syncthreads();
  {
    half_t* Uo = U + ((size_t)bh * NC + c) * (ND * ND);
    int d = t >> 2, v0 = (t & 3) * 16;
    f16x8 u0 = *(const f16x8*)&KT[d * 72 + v0];
    f16x8 u1 = *(const f16x8*)&KT[d * 72 + v0 + 8];
    *(f16x8*)&Uo[d * 64 + v0] = u0;
    *(f16x8*)&Uo[d * 64 + v0 + 8] = u1;
  }
}

// ---- parallel state scan: P_0 = hin; P_{c+1} = f_c*P_c + U_c; hout = P_16 ----
// 131k independent (bh,d,v) chains; thread owns one element, 16-step serial
// recurrence in registers. Grid (16, 32) x 256 thr. Coalesced U/Ph access.
__global__ __launch_bounds__(256) void pscan_kernel(
    const half_t* __restrict__ U, const float* __restrict__ fbuf,
    const float* __restrict__ hin, float* __restrict__ hout,
    half_t* __restrict__ Ph) {
  const int bh = blockIdx.y;
  const int i = blockIdx.x * 256 + threadIdx.x;  // [0,4096)
  float P = hin[(size_t)bh * 4096 + i];
  const half_t* Ub = U + (size_t)bh * NC * 4096 + i;
  half_t* Pb = Ph + (size_t)bh * NC * 4096 + i;
  const float* fb = fbuf + bh * NC;
#pragma unroll
  for (int c = 0; c < NC; c++) {
    Pb[c * 4096] = (half_t)P;
    P = fb[c] * P + (float)Ub[c * 4096];
  }
  hout[(size_t)bh * 4096 + i] = P;
}

// -- retention pass 2+3: per-chunk QK^T decay + inner@V + cross@P + gn + gate.
// P_c comes precomputed (fp16). Vectorized epilogue via PT bounce.
__global__ __launch_bounds__(256) void ret_pass23_kernel(
    const half_t* __restrict__ qmat, const half_t* __restrict__ kmat,
    const half_t* __restrict__ vmat, const half_t* __restrict__ Ph,
    const half_t* __restrict__ gmat, const int* __restrict__ seg,
    const int* __restrict__ ts, const float* __restrict__ gns,
    const float* __restrict__ gnb, half_t* __restrict__ y16) {
  __shared__ half_t Qs[64 * 72];
  __shared__ half_t KS[64 * 72];
  __shared__ half_t VT[64 * 72];
  __shared__ half_t PT[64 * 72];
  __shared__ int segs[64];
  __shared__ int tss[64];
  __shared__ float gnsv[64];
  __shared__ float gnbv[64];
  const int c = blockIdx.x, bh = blockIdx.y;
  const int b = bh >> 3, h = bh & 7;
  const float l2k = h_log2kap(h);
  const int t = threadIdx.x;
  const int r = t & 63, qd = t >> 6;
  {
    size_t gbase = (size_t)(b * NS + c * CSZ + r) * NE + h * ND + qd * 16;
    f16x8 q0 = *(const f16x8*)&qmat[gbase];
    f16x8 q1 = *(const f16x8*)&qmat[gbase + 8];
    *(f16x8*)&Qs[r * 72 + qd * 16] = q0;
    *(f16x8*)&Qs[r * 72 + qd * 16 + 8] = q1;
    f16x8 k0 = *(const f16x8*)&kmat[gbase];
    f16x8 k1 = *(const f16x8*)&kmat[gbase + 8];
    *(f16x8*)&KS[r * 72 + qd * 16] = k0;
    *(f16x8*)&KS[r * 72 + qd * 16 + 8] = k1;
    f16x8 v0 = *(const f16x8*)&vmat[gbase];
    f16x8 v1 = *(const f16x8*)&vmat[gbase + 8];
    const half_t* php = Ph + ((size_t)bh * NC + c) * 4096 + r * 64 + qd * 16;
    f16x8 p0 = *(const f16x8*)php;
    f16x8 p1 = *(const f16x8*)(php + 8);
#pragma unroll
    for (int s = 0; s < 8; s++) {
      VT[(qd * 16 + s) * 72 + r] = v0[s];
      VT[(qd * 16 + 8 + s) * 72 + r] = v1[s];
      PT[(qd * 16 + s) * 72 + r] = p0[s];
      PT[(qd * 16 + 8 + s) * 72 + r] = p1[s];
    }
    if (t < 64) {
      segs[t] = seg[b * NS + c * CSZ + t];
      tss[t] = ts[b * NS + c * CSZ + t];
    } else if (t < 128) {
      gnsv[t - 64] = gns[h * ND + t - 64];
      gnbv[t - 64] = gnb[h * ND + t - 64];
    }
  }
  __syncthreads();
  const int lane = t & 63, wv = t >> 6;
  const int fr = lane & 15, fo8 = (lane >> 4) * 8;
  f32x4 aq[4];
#pragma unroll
  for (int j = 0; j < 4; j++) aq[j] = (f32x4){0.f, 0.f, 0.f, 0.f};
#pragma unroll
  for (int ks = 0; ks < 2; ks++) {
    f16x8 af = *(const f16x8*)&Qs[(wv * 16 + fr) * 72 + ks * 32 + fo8];
#pragma unroll
    for (int nt = 0; nt < 4; nt++) {
      f16x8 bf = *(const f16x8*)&KS[(nt * 16 + fr) * 72 + ks * 32 + fo8];
      aq[nt] = __builtin_amdgcn_mfma_f32_16x16x32_f16(af, bf, aq[nt], 0, 0, 0);
    }
  }
  __syncthreads();
  const int qrow = wv * 16 + (lane >> 4) * 4;
#pragma unroll
  for (int nt = 0; nt < 4; nt++) {
    int j = nt * 16 + fr;
    int sj = segs[j];
    float tsj = (float)tss[j];
#pragma unroll
    for (int rg = 0; rg < 4; rg++) {
      int i = qrow + rg;
      float w = 0.0f;
      if (j <= i && sj == segs[i]) w = exp2f(((float)tss[i] - tsj) * l2k);
      KS[i * 72 + j] = (half_t)(aq[nt][rg] * w);
    }
  }
  __syncthreads();
  float gi;
  {
    int ps = 0;
    float pt = -1.0f;
    if (c > 0) {
      ps = seg[b * NS + c * CSZ - 1];
      pt = (float)ts[b * NS + c * CSZ - 1];
    }
    int i = wv * 16 + fr;
    gi = (segs[i] == ps) ? exp2f(((float)tss[i] - pt) * l2k) : 0.0f;
  }
  f32x4 acc[4];
#pragma unroll
  for (int j = 0; j < 4; j++) acc[j] = (f32x4){0.f, 0.f, 0.f, 0.f};
#pragma unroll
  for (int ks = 0; ks < 2; ks++) {
    f16x8 saf = *(const f16x8*)&KS[(wv * 16 + fr) * 72 + ks * 32 + fo8];
    f16x8 qaf = *(const f16x8*)&Qs[(wv * 16 + fr) * 72 + ks * 32 + fo8];
    f16x8 gqf;
#pragma unroll
    for (int e = 0; e < 8; e++) gqf[e] = (half_t)(gi * (float)qaf[e]);
#pragma unroll
    for (int nt = 0; nt < 4; nt++) {
      f16x8 vbf = *(const f16x8*)&VT[(nt * 16 + fr) * 72 + ks * 32 + fo8];
      acc[nt] = __builtin_amdgcn_mfma_f32_16x16x32_f16(saf, vbf, acc[nt], 0, 0, 0);
      f16x8 pbf = *(const f16x8*)&PT[(nt * 16 + fr) * 72 + ks * 32 + fo8];
      acc[nt] = __builtin_amdgcn_mfma_f32_16x16x32_f16(gqf, pbf, acc[nt], 0, 0, 0);
    }
  }
  __syncthreads();  // PT reads done; reuse as epilogue bounce
#pragma unroll
  for (int rg = 0; rg < 4; rg++) {
    float s1 = acc[0][rg] + acc[1][rg] + acc[2][rg] + acc[3][rg];
    float s2 = acc[0][rg] * acc[0][rg] + acc[1][rg] * acc[1][rg] +
               acc[2][rg] * acc[2][rg] + acc[3][rg] * acc[3][rg];
    s1 += __shfl_xor(s1, 1); s2 += __shfl_xor(s2, 1);
    s1 += __shfl_xor(s1, 2); s2 += __shfl_xor(s2, 2);
    s1 += __shfl_xor(s1, 4); s2 += __shfl_xor(s2, 4);
    s1 += __shfl_xor(s1, 8); s2 += __shfl_xor(s2, 8);
    float mu = s1 * (1.0f / 64.0f);
    float var = s2 * (1.0f / 64.0f) - mu * mu;
    float rs = rsqrtf(var + FEPS);
    int i = qrow + rg;
#pragma unroll
    for (int nt = 0; nt < 4; nt++) {
      int col = nt * 16 + fr;
      PT[i * 72 + col] = (half_t)((acc[nt][rg] - mu) * rs * gnsv[col] + gnbv[col]);
    }
  }
  __syncthreads();
  {
    int row = t >> 2, col0 = (t & 3) * 16;
    size_t gb2 = (size_t)(b * NS + c * CSZ + row) * NE + h * ND + col0;
    f16x8 g0 = *(const f16x8*)&gmat[gb2];
    f16x8 g1 = *(const f16x8*)&gmat[gb2 + 8];
    f16x8 v0 = *(const f16x8*)&PT[row * 72 + col0];
    f16x8 v1 = *(const f16x8*)&PT[row * 72 + col0 + 8];
    f16x8 o0, o1;
#pragma unroll
    for (int e2 = 0; e2 < 8; e2++) {
      o0[e2] = (half_t)(silu_f((float)g0[e2]) * (float)v0[e2]);
      o1[e2] = (half_t)(silu_f((float)g1[e2]) * (float)v1[e2]);
    }
    *(f16x8*)&y16[gb2] = o0;
    *(f16x8*)&y16[gb2 + 8] = o1;
  }
}

extern "C" void kernel_launch(void* const* d_in, const int* in_sizes, int n_in,
                              void* d_out, int out_size, void* d_ws, size_t ws_size,
                              hipStream_t stream) {
  (void)in_sizes; (void)n_in; (void)out_size; (void)ws_size;
  const float* x = (const float*)d_in[0];
  const float* obs = (const float*)d_in[1];
  const float* hs1 = (const float*)d_in[2];
  const float* hs2 = (const float*)d_in[3];
  const int* dones = (const int*)d_in[4];
  const int* tsid = (const int*)d_in[5];
  const float* ln1 = (const float*)d_in[6];
  const float* ln2 = (const float*)d_in[7];
  const float* ln3 = (const float*)d_in[8];
  const float* r1_gs = (const float*)d_in[14];
  const float* r1_gb = (const float*)d_in[15];
  const float* r2_gs = (const float*)d_in[21];
  const float* r2_gb = (const float*)d_in[22];

  const size_t NBUF = (size_t)NB * NS * NE;  // 2,097,152 elements
  char* ws = (char*)d_ws;
  int* segb = (int*)ws;                              // 16 KB
  float* fb = (float*)(ws + 16384);                  // 2 KB
  half_t* W16 = (half_t*)(ws + 18432);               // 13 x 512 KB
  char* p = ws + 18432 + (size_t)13 * NE * NE * sizeof(half_t);
  float* F1 = (float*)p;                 // y (fp32 residual for final rms)
  half_t* Uh = (half_t*)(F1 + NBUF);     // U (fp16), 4 MB
  half_t* Ph = Uh + NBUF;                // P_c scan states (fp16), 4 MB
  half_t* Hq = Ph + NBUF;
  half_t* Hk = Hq + NBUF;
  half_t* Hv = Hk + NBUF;
  half_t* Hg = Hv + NBUF;
  half_t* H1 = Hg + NBUF;                // pass3 output (gated, fp16)
  half_t* H2 = H1 + NBUF;                // rms fp16 output
  half_t* Hx = H2 + NBUF;                // x fp16
  half_t* Hobs = Hx + NBUF;              // obs fp16
  half_t* Hq2 = Hobs + NBUF;             // layer-2 q (computed early)
  half_t* Hg2 = Hq2 + NBUF;              // layer-2 g (computed early)

  float* out = (float*)d_out;
  float* hs1o = out + NBUF;
  float* hs2o = hs1o + (size_t)NB * NH * ND * ND;

  WCArgs wc;
  wc.src[0] = (const float*)d_in[9];   wc.src[1] = (const float*)d_in[10];
  wc.src[2] = (const float*)d_in[11];  wc.src[3] = (const float*)d_in[12];
  wc.src[4] = (const float*)d_in[13];  wc.src[5] = (const float*)d_in[16];
  wc.src[6] = (const float*)d_in[17];  wc.src[7] = (const float*)d_in[18];
  wc.src[8] = (const float*)d_in[19];  wc.src[9] = (const float*)d_in[20];
  wc.src[10] = (const float*)d_in[24]; wc.src[11] = (const float*)d_in[23];
  wc.src[12] = (const float*)d_in[25];
  wc.dst = W16;
  wc.dones = dones;
  wc.seg = segb;
  wc.x = x; wc.obs = obs; wc.hx = Hx; wc.hobs = Hobs;
  const half_t* WS[13];
  for (int i = 0; i < 13; i++) WS[i] = W16 + (size_t)i * NE * NE;

  dim3 gR(16, 32);

  prep_kernel<<<1860, 256, 0, stream>>>(wc);

  // ---- GEMM-1 (6 fused): layer1 q,k,v,g from x16; layer2 q2,g2 from obs16 ----
  {
    GArgs a;
    a.A[0] = Hx;   a.W[0] = WS[0]; a.O[0] = Hq;  a.al[0] = 1.0f;
    a.A[1] = Hx;   a.W[1] = WS[1]; a.O[1] = Hk;  a.al[1] = 0.125f;
    a.A[2] = Hx;   a.W[2] = WS[2]; a.O[2] = Hv;  a.al[2] = 1.0f;
    a.A[3] = Hx;   a.W[3] = WS[3]; a.O[3] = Hg;  a.al[3] = 1.0f;
    a.A[4] = Hobs; a.W[4] = WS[5]; a.O[4] = Hq2; a.al[4] = 1.0f;
    a.A[5] = Hobs; a.W[5] = WS[8]; a.O[5] = Hg2; a.al[5] = 1.0f;
    a.A[6] = Hx;   a.W[6] = WS[0]; a.O[6] = Hq;  a.al[6] = 1.0f;  // unused
    a.A[7] = Hx;   a.W[7] = WS[0]; a.O[7] = Hq;  a.al[7] = 1.0f;  // unused
    mfma_gemm_kernel<<<dim3(24, 64), 256, 0, stream>>>(a);
  }
  ret_pass1_kernel<<<gR, 256, 0, stream>>>(Hk, Hv, segb, tsid, Uh, fb);
  pscan_kernel<<<gR, 256, 0, stream>>>(Uh, fb, hs1, hs1o, Ph);
  ret_pass23_kernel<<<gR, 256, 0, stream>>>(Hq, Hk, Hv, Ph, Hg, segb, tsid,
                                            r1_gs, r1_gb, H1);
  // o1 + rms1 fused: x2 = rms(x + H1@wo1) -> H2 (fp16)
  oproj_rms_kernel<0, 1><<<256, 512, 0, stream>>>(H1, nullptr, WS[4], x, ln1,
                                                  nullptr, H2);

  // ---- GEMM-2 (2 fused): k2,v2 = x2 @ {wk2,wv2} ----
  {
    GArgs a;
    a.A[0] = H2; a.W[0] = WS[6]; a.O[0] = Hk; a.al[0] = 0.125f;
    a.A[1] = H2; a.W[1] = WS[7]; a.O[1] = Hv; a.al[1] = 1.0f;
    a.A[2] = H2; a.W[2] = WS[6]; a.O[2] = Hk; a.al[2] = 0.125f;  // unused
    a.A[3] = H2; a.W[3] = WS[6]; a.O[3] = Hk; a.al[3] = 0.125f;  // unused
    a.A[4] = H2; a.W[4] = WS[6]; a.O[4] = Hk; a.al[4] = 0.125f;
    a.A[5] = H2; a.W[5] = WS[6]; a.O[5] = Hk; a.al[5] = 0.125f;
    a.A[6] = H2; a.W[6] = WS[6]; a.O[6] = Hk; a.al[6] = 0.125f;
    a.A[7] = H2; a.W[7] = WS[6]; a.O[7] = Hk; a.al[7] = 0.125f;
    mfma_gemm_kernel<<<dim3(8, 64), 256, 0, stream>>>(a);
  }
  ret_pass1_kernel<<<gR, 256, 0, stream>>>(Hk, Hv, segb, tsid, Uh, fb);
  pscan_kernel<<<gR, 256, 0, stream>>>(Uh, fb, hs2, hs2o, Ph);
  ret_pass23_kernel<<<gR, 256, 0, stream>>>(Hq2, Hk, Hv, Ph, Hg2, segb, tsid,
                                            r2_gs, r2_gb, H1);
  // o2 + rms2 fused: y = rms(obs + H1@wo2) -> F1 (fp32) + H2 (fp16)
  oproj_rms_kernel<0, 2><<<256, 512, 0, stream>>>(H1, nullptr, WS[9], obs, ln2,
                                                  F1, H2);

  // ---- FFN part A (2 fused): gate = y@wg -> Hq, lin = y@wl -> Hk ----
  {
    GArgs a;
    a.A[0] = H2; a.W[0] = WS[10]; a.O[0] = Hq; a.al[0] = 1.0f;
    a.A[1] = H2; a.W[1] = WS[11]; a.O[1] = Hk; a.al[1] = 1.0f;
    a.A[2] = H2; a.W[2] = WS[10]; a.O[2] = Hq; a.al[2] = 1.0f;  // unused
    a.A[3] = H2; a.W[3] = WS[10]; a.O[3] = Hq; a.al[3] = 1.0f;  // unused
    a.A[4] = H2; a.W[4] = WS[10]; a.O[4] = Hq; a.al[4] = 1.0f;
    a.A[5] = H2; a.W[5] = WS[10]; a.O[5] = Hq; a.al[5] = 1.0f;
    a.A[6] = H2; a.W[6] = WS[10]; a.O[6] = Hq; a.al[6] = 1.0f;
    a.A[7] = H2; a.W[7] = WS[10]; a.O[7] = Hq; a.al[7] = 1.0f;
    mfma_gemm_kernel<<<dim3(8, 64), 256, 0, stream>>>(a);
  }
  // FFN part B + final rms fused: out = rms(y + (silu(Hq)*Hk)@wo3)
  oproj_rms_kernel<3, 0><<<256, 512, 0, stream>>>(Hq, Hk, WS[12], F1, ln3,
                                                  out, nullptr);
}